// Round 9
// baseline (2117.396 us; speedup 1.0000x reference)
//
#include <hip/hip_runtime.h>

typedef unsigned short u16;
typedef unsigned int u32;
typedef unsigned char u8;
typedef __attribute__((ext_vector_type(8))) short short8v;   // 8 bf16 (4 VGPRs)
typedef __attribute__((ext_vector_type(4))) float f32x4;

#define MFMA16(a,b,c) __builtin_amdgcn_mfma_f32_16x16x32_bf16((a),(b),(c),0,0,0)

__device__ __forceinline__ u16 f2bf(float f){
  u32 u = __float_as_uint(f);
  return (u16)((u + 0x7fffu + ((u >> 16) & 1u)) >> 16);   // RNE
}
__device__ __forceinline__ float bf2f(u16 h){ return __uint_as_float(((u32)h) << 16); }
__device__ __forceinline__ float gelu_f(float x){ return 0.5f * x * (1.f + erff(x * 0.70710678118654752f)); }
__device__ __forceinline__ float sigm_f(float x){ return 1.f / (1.f + __expf(-x)); }
__device__ __forceinline__ void acc4(float4& a, const float4 b){ a.x+=b.x; a.y+=b.y; a.z+=b.z; a.w+=b.w; }

// ---- fp8 e4m3 software codec. Layout: s@7 | E@3-6 | m@0-2  (R8 fix: e<<3, was e<<4) ----
__device__ __forceinline__ u8 enc8(float f){
  u32 u = __float_as_uint(f);
  u32 s = (u >> 24) & 0x80u;
  u32 mag = u & 0x7fffffffu;
  if (mag > 0x43E00000u) mag = 0x43E00000u;              // clamp to 448
  mag += 0x7ffffu + ((mag >> 20) & 1u);                  // RNE at bit 20
  int e = (int)(mag >> 23) - 120;
  u32 m = (mag >> 20) & 7u;
  if (e <= 0) return (u8)s;                              // flush-to-zero
  return (u8)(s | ((u32)e << 3) | m);
}
__device__ __forceinline__ float dec8(u32 b){
  return __uint_as_float(((b & 0x80u) << 24) | (((b & 0x7fu) << 20) + 0x3C000000u));
}

// async global->LDS, 16B per lane (HW: wave-uniform LDS base + lane*16)
__device__ __forceinline__ void gl16(const void* g, void* l){
  __builtin_amdgcn_global_load_lds((const __attribute__((address_space(1))) u32*)g,
                                   (__attribute__((address_space(3))) u32*)l, 16, 0, 0);
}

// ---------------- fused weight cast fp32 -> bf16 (12 jobs, one launch) ----------------
struct CastJobs { const float* s[12]; u16* d[12]; int start[13]; };
__global__ __launch_bounds__(256) void cast_all_k(CastJobs J){
  int bx = blockIdx.x, j = 0;
  #pragma unroll
  for (int t = 0; t < 12; t++) if (bx >= J.start[t + 1]) j = t + 1;
  int i = (bx - J.start[j]) * 1024 + threadIdx.x * 4;
  float4 v = *(const float4*)(J.s[j] + i);
  ushort4 o; o.x = f2bf(v.x); o.y = f2bf(v.y); o.z = f2bf(v.z); o.w = f2bf(v.w);
  *(ushort4*)(J.d[j] + i) = o;
}

__global__ __launch_bounds__(256) void cast_k(const float* __restrict__ s, u16* __restrict__ d, int n){
  int i = (blockIdx.x * 256 + threadIdx.x) * 4;
  if (i + 3 < n){
    float4 v = *(const float4*)(s + i);
    ushort4 o; o.x = f2bf(v.x); o.y = f2bf(v.y); o.z = f2bf(v.z); o.w = f2bf(v.w);
    *(ushort4*)(d + i) = o;
  }
}

// ---------------- transpose-cast 1024x1024 fp32 -> bf16^T ----------------
__global__ __launch_bounds__(256) void tcast_k(const float* __restrict__ s, u16* __restrict__ d){
  __shared__ float tile[32][33];
  int bx = blockIdx.x & 31, by = blockIdx.x >> 5;
  int tx = threadIdx.x & 31, ty = threadIdx.x >> 5;     // 32 x 8
  #pragma unroll
  for (int i = 0; i < 4; i++)
    tile[ty + i * 8][tx] = s[(size_t)(by * 32 + ty + i * 8) * 1024 + bx * 32 + tx];
  __syncthreads();
  #pragma unroll
  for (int i = 0; i < 4; i++)
    d[(size_t)(bx * 32 + ty + i * 8) * 1024 + by * 32 + tx] = f2bf(tile[tx][ty + i * 8]);
}

// ---------------- bias2 = gen_b1 + gw1 @ aob ----------------
__global__ __launch_bounds__(256) void bias2_k(const float* __restrict__ gw1, const float* __restrict__ aob,
                                               const float* __restrict__ gb1, float* __restrict__ out){
  int j = blockIdx.x * 32 + (threadIdx.x >> 3);      // 64 blocks -> 2048 outputs
  int l8 = threadIdx.x & 7;
  const float* r = gw1 + (size_t)j * 1024;
  float acc = 0.f;
  #pragma unroll 8
  for (int kk = 0; kk < 32; kk++){
    int k = kk * 32 + l8 * 4;
    float4 a = *(const float4*)(r + k);
    float4 w = *(const float4*)(aob + k);
    acc += a.x * w.x + a.y * w.y + a.z * w.z + a.w * w.w;
  }
  acc += __shfl_xor(acc, 1); acc += __shfl_xor(acc, 2); acc += __shfl_xor(acc, 4);
  if (l8 == 0) out[j] = gb1[j] + acc;
}

// ---------------- init ----------------
__global__ __launch_bounds__(256) void init_k(const float* __restrict__ comp, float* ps0, float* outp,
                                              float* h0, float* c0, float* h1, float* c1){
  int i = blockIdx.x * 256 + threadIdx.x;       // 32768
  int b = i >> 10, hh = i & 1023;
  float v = comp[(size_t)b * 1048576 + hh];
  ps0[i] = v; outp[i] = v;
  h0[i] = 0.f; c0[i] = 0.f; h1[i] = 0.f; c1[i] = 0.f;
}

// ---------------- fused K/V GEMM -> fp8 outputs. K8:[b][hd][s], V8:[b][h][s][d] ----------------
__global__ __launch_bounds__(256) void gemmkv_k(const u16* __restrict__ compb,
    const u16* __restrict__ Wk, const u16* __restrict__ Wv,
    const float* __restrict__ bk, const float* __restrict__ bv,
    u8* __restrict__ K8, u8* __restrict__ V8)
{
  __shared__ u16 Sh[16384];               // As(16KB) + Bs(16KB); reused as bf16 C-tile (32KB)
  u16* As = Sh;
  u16* Bs = Sh + 8192;
  int tid = threadIdx.x;
  int x = blockIdx.x;
  int xcd = x & 7, p = x >> 3;
  int cpanel = xcd * 32 + (p >> 3);
  int wpanel = p & 7;
  int isK = (blockIdx.z != 0);
  const u16 *msrc, *nsrc; int m0, n0;
  if (!isK){ m0 = cpanel * 128; n0 = wpanel * 128; msrc = compb; nsrc = Wv; }
  else     { m0 = wpanel * 128; n0 = cpanel * 128; msrc = Wk;    nsrc = compb; }

  int w = tid >> 6, l = tid & 63, lr = l & 15, lk = l >> 4;
  int wm = (w >> 1) * 64, wn = (w & 1) * 64;
  f32x4 acc[4][4];
  #pragma unroll
  for (int i = 0; i < 4; i++)
    #pragma unroll
    for (int j = 0; j < 4; j++) acc[i][j] = (f32x4){0.f,0.f,0.f,0.f};

  for (int kc = 0; kc < 1024; kc += 64){
    #pragma unroll
    for (int r = 0; r < 4; r++){
      int s = tid + r * 256;
      int row = s >> 3, pp = s & 7;
      int lg = pp ^ (row & 7);
      gl16(msrc + (size_t)(m0 + row) * 1024 + kc + lg * 8, As + s * 8);
      gl16(nsrc + (size_t)(n0 + row) * 1024 + kc + lg * 8, Bs + s * 8);
    }
    __syncthreads();
    #pragma unroll
    for (int kk = 0; kk < 2; kk++){
      short8v a[4], bb[4];
      #pragma unroll
      for (int mi = 0; mi < 4; mi++){
        int row = wm + mi * 16 + lr;
        int ph = (kk * 4 + lk) ^ (row & 7);
        a[mi] = *(const short8v*)(As + row * 64 + ph * 8);
      }
      #pragma unroll
      for (int ni = 0; ni < 4; ni++){
        int row = wn + ni * 16 + lr;
        int ph = (kk * 4 + lk) ^ (row & 7);
        bb[ni] = *(const short8v*)(Bs + row * 64 + ph * 8);
      }
      #pragma unroll
      for (int mi = 0; mi < 4; mi++)
        #pragma unroll
        for (int ni = 0; ni < 4; ni++)
          acc[mi][ni] = MFMA16(a[mi], bb[ni], acc[mi][ni]);
    }
    __syncthreads();
  }
  // stage bf16 C-tile (with bias), then fp8-encode + coalesced 16B stores
  #pragma unroll
  for (int mi = 0; mi < 4; mi++)
    #pragma unroll
    for (int ni = 0; ni < 4; ni++)
      #pragma unroll
      for (int r = 0; r < 4; r++){
        int row = wm + mi * 16 + lk * 4 + r;
        int col = wn + ni * 16 + lr;
        float bias = isK ? bk[m0 + row] : bv[n0 + col];
        Sh[row * 128 + col] = f2bf(acc[mi][ni][r] + bias);
      }
  __syncthreads();
  for (int i = tid; i < 1024; i += 256){
    int r = i >> 3, c16 = (i & 7) * 16;
    short8v s0 = *(const short8v*)(Sh + r * 128 + c16);
    short8v s1 = *(const short8v*)(Sh + r * 128 + c16 + 8);
    uint4 o;
    u32 w0 = 0, w1 = 0, w2 = 0, w3 = 0;
    #pragma unroll
    for (int e = 0; e < 4; e++){
      w0 |= (u32)enc8(bf2f((u16)s0[e]))     << (8 * e);
      w1 |= (u32)enc8(bf2f((u16)s0[e + 4])) << (8 * e);
      w2 |= (u32)enc8(bf2f((u16)s1[e]))     << (8 * e);
      w3 |= (u32)enc8(bf2f((u16)s1[e + 4])) << (8 * e);
    }
    o.x = w0; o.y = w1; o.z = w2; o.w = w3;
    if (!isK){
      int bs = m0 + r, hd = n0 + c16;
      int bb2 = bs >> 10, s = bs & 1023;
      int hh = hd >> 6, dl = hd & 63;
      *(uint4*)(V8 + (((size_t)(bb2 * 16 + hh) * 1024 + s) * 64 + dl)) = o;
    } else {
      int hd = m0 + r, bs = n0 + c16;
      int bb2 = bs >> 10, s = bs & 1023;
      *(uint4*)(K8 + ((size_t)(bb2 * 1024 + hd) * 1024 + s)) = o;
    }
  }
}

// ---------------- gaw = gw1 @ aow  (A[2048x1024] @ B^T where B = aow^T) ----------------
__global__ __launch_bounds__(256) void gemmbb_k(const u16* __restrict__ A, const u16* __restrict__ B,
                                                u16* __restrict__ C)
{
  __shared__ u16 As[128 * 64];
  __shared__ u16 Bs[128 * 64];
  int tid = threadIdx.x;
  int m0 = blockIdx.x * 128, n0 = blockIdx.y * 128;
  int w = tid >> 6, l = tid & 63, lr = l & 15, lk = l >> 4;
  int wm = (w >> 1) * 64, wn = (w & 1) * 64;
  f32x4 acc[4][4];
  #pragma unroll
  for (int i = 0; i < 4; i++)
    #pragma unroll
    for (int j = 0; j < 4; j++) acc[i][j] = (f32x4){0.f,0.f,0.f,0.f};
  for (int kc = 0; kc < 1024; kc += 64){
    #pragma unroll
    for (int r = 0; r < 4; r++){
      int s = tid + r * 256;
      int row = s >> 3, pp = s & 7;
      int lg = pp ^ (row & 7);
      gl16(A + (size_t)(m0 + row) * 1024 + kc + lg * 8, As + s * 8);
      gl16(B + (size_t)(n0 + row) * 1024 + kc + lg * 8, Bs + s * 8);
    }
    __syncthreads();
    #pragma unroll
    for (int kk = 0; kk < 2; kk++){
      short8v a[4], bb[4];
      #pragma unroll
      for (int mi = 0; mi < 4; mi++){
        int row = wm + mi * 16 + lr;
        int ph = (kk * 4 + lk) ^ (row & 7);
        a[mi] = *(const short8v*)(As + row * 64 + ph * 8);
      }
      #pragma unroll
      for (int ni = 0; ni < 4; ni++){
        int row = wn + ni * 16 + lr;
        int ph = (kk * 4 + lk) ^ (row & 7);
        bb[ni] = *(const short8v*)(Bs + row * 64 + ph * 8);
      }
      #pragma unroll
      for (int mi = 0; mi < 4; mi++)
        #pragma unroll
        for (int ni = 0; ni < 4; ni++)
          acc[mi][ni] = MFMA16(a[mi], bb[ni], acc[mi][ni]);
    }
    __syncthreads();
  }
  #pragma unroll
  for (int mi = 0; mi < 4; mi++)
    #pragma unroll
    for (int ni = 0; ni < 4; ni++)
      #pragma unroll
      for (int r = 0; r < 4; r++){
        int row = m0 + wm + mi * 16 + lk * 4 + r;
        int col = n0 + wn + ni * 16 + lr;
        C[(size_t)row * 1024 + col] = f2bf(acc[mi][ni][r]);
      }
}

// ---------------- M=32 MFMA linear tile body (256 threads / 4 waves) ----------------
struct LinSeg {
  const float* X0; const float* Xa; const float* Xb; const float* Xc;
  const u16* W1; const float* b1;
  const float* Y; const u16* W2; const float* b2;
  float* out; float* out2;
  int K1, ld1, K2, ld2, N, act, gate;   // act: 0 none, 1 gelu, 2 scale
  float scale;
  float* stats;
  const float* lng; const float* lnb; const float* lnstats;
  const float* cprev; float* cout; float* hout;
};

__device__ __forceinline__ short8v pack8(float4 v0, float4 v1){
  short8v r;
  r[0]=(short)f2bf(v0.x); r[1]=(short)f2bf(v0.y); r[2]=(short)f2bf(v0.z); r[3]=(short)f2bf(v0.w);
  r[4]=(short)f2bf(v1.x); r[5]=(short)f2bf(v1.y); r[6]=(short)f2bf(v1.z); r[7]=(short)f2bf(v1.w);
  return r;
}

__device__ __forceinline__ short8v load_sum8(const LinSeg& S, int row, int kb){
  size_t o = (size_t)row * S.K1 + kb;
  float4 v0 = *(const float4*)(S.X0 + o);
  float4 v1 = *(const float4*)(S.X0 + o + 4);
  if (S.lng){
    float mu = S.lnstats[row] * (1.f / 2048.f);
    float ms = S.lnstats[32 + row] * (1.f / 2048.f);
    float rstd = rsqrtf(ms - mu * mu + 1e-5f);
    float4 g0 = *(const float4*)(S.lng + kb), g1 = *(const float4*)(S.lng + kb + 4);
    float4 b0 = *(const float4*)(S.lnb + kb), b1 = *(const float4*)(S.lnb + kb + 4);
    v0.x = gelu_f((v0.x - mu) * rstd * g0.x + b0.x);
    v0.y = gelu_f((v0.y - mu) * rstd * g0.y + b0.y);
    v0.z = gelu_f((v0.z - mu) * rstd * g0.z + b0.z);
    v0.w = gelu_f((v0.w - mu) * rstd * g0.w + b0.w);
    v1.x = gelu_f((v1.x - mu) * rstd * g1.x + b1.x);
    v1.y = gelu_f((v1.y - mu) * rstd * g1.y + b1.y);
    v1.z = gelu_f((v1.z - mu) * rstd * g1.z + b1.z);
    v1.w = gelu_f((v1.w - mu) * rstd * g1.w + b1.w);
  } else {
    if (S.Xa){ acc4(v0, *(const float4*)(S.Xa + o)); acc4(v1, *(const float4*)(S.Xa + o + 4)); }
    if (S.Xb){ acc4(v0, *(const float4*)(S.Xb + o)); acc4(v1, *(const float4*)(S.Xb + o + 4)); }
    if (S.Xc){ acc4(v0, *(const float4*)(S.Xc + o)); acc4(v1, *(const float4*)(S.Xc + o + 4)); }
  }
  return pack8(v0, v1);
}
__device__ __forceinline__ short8v load_y8(const float* p){
  return pack8(*(const float4*)(p), *(const float4*)(p + 4));
}

typedef float Red4[32][32];    // red[4][32][32] = 16KB

__device__ void lin_body(const LinSeg& S, int bi, int tid, Red4* red){
  int c0 = bi * 32, j0 = bi * 8;
  int w = tid >> 6, l = tid & 63, lr = l & 15, lk = l >> 4;
  int wc0 = S.gate ? ((lr >> 3) << 10) + j0 + (lr & 7) : c0 + lr;
  int wc1 = S.gate ? (((lr + 16) >> 3) << 10) + j0 + ((lr + 16) & 7) : c0 + lr + 16;
  f32x4 acc[2][2];
  #pragma unroll
  for (int i = 0; i < 2; i++)
    #pragma unroll
    for (int j = 0; j < 2; j++) acc[i][j] = (f32x4){0.f,0.f,0.f,0.f};

  {
    int chunk = S.K1 >> 2;
    int kb0 = w * chunk + lk * 8;
    for (int kk = 0; kk < chunk; kk += 32){
      int kb = kb0 + kk;
      short8v a0 = load_sum8(S, lr, kb);
      short8v a1 = load_sum8(S, lr + 16, kb);
      short8v w0 = *(const short8v*)(S.W1 + (size_t)wc0 * S.ld1 + kb);
      short8v w1 = *(const short8v*)(S.W1 + (size_t)wc1 * S.ld1 + kb);
      acc[0][0] = MFMA16(a0, w0, acc[0][0]);
      acc[0][1] = MFMA16(a0, w1, acc[0][1]);
      acc[1][0] = MFMA16(a1, w0, acc[1][0]);
      acc[1][1] = MFMA16(a1, w1, acc[1][1]);
    }
  }
  if (S.Y){
    int chunk = S.K2 >> 2;
    int kb0 = w * chunk + lk * 8;
    for (int kk = 0; kk < chunk; kk += 32){
      int kb = kb0 + kk;
      short8v a0 = load_y8(S.Y + (size_t)lr * S.K2 + kb);
      short8v a1 = load_y8(S.Y + (size_t)(lr + 16) * S.K2 + kb);
      short8v w0 = *(const short8v*)(S.W2 + (size_t)wc0 * S.ld2 + kb);
      short8v w1 = *(const short8v*)(S.W2 + (size_t)wc1 * S.ld2 + kb);
      acc[0][0] = MFMA16(a0, w0, acc[0][0]);
      acc[0][1] = MFMA16(a0, w1, acc[0][1]);
      acc[1][0] = MFMA16(a1, w0, acc[1][0]);
      acc[1][1] = MFMA16(a1, w1, acc[1][1]);
    }
  }
  #pragma unroll
  for (int mi = 0; mi < 2; mi++)
    #pragma unroll
    for (int ni = 0; ni < 2; ni++)
      #pragma unroll
      for (int r = 0; r < 4; r++)
        red[w][mi * 16 + lk * 4 + r][ni * 16 + lr] = acc[mi][ni][r];
  __syncthreads();
  if (S.gate){
    int row = tid >> 3, j = tid & 7;
    float s[4];
    #pragma unroll
    for (int g = 0; g < 4; g++){
      float v = 0.f;
      #pragma unroll
      for (int ww = 0; ww < 4; ww++) v += red[ww][row][g * 8 + j];
      s[g] = v;
    }
    int gc = j0 + j;
    float gI = s[0] + S.b1[gc]        + S.b2[gc];
    float gF = s[1] + S.b1[1024 + gc] + S.b2[1024 + gc];
    float gG = s[2] + S.b1[2048 + gc] + S.b2[2048 + gc];
    float gO = s[3] + S.b1[3072 + gc] + S.b2[3072 + gc];
    int idx = row * 1024 + gc;
    float cN = sigm_f(gF) * S.cprev[idx] + sigm_f(gI) * tanhf(gG);
    S.cout[idx] = cN;
    S.hout[idx] = sigm_f(gO) * tanhf(cN);
    return;
  }
  float vout[4]; int iout[4];
  int cnt = 0;
  for (int i = tid; i < 1024; i += 256){
    int row = i >> 5, col = i & 31;
    float v = 0.f;
    #pragma unroll
    for (int ww = 0; ww < 4; ww++) v += red[ww][row][col];
    v += S.b1[c0 + col];
    if (S.b2) v += S.b2[c0 + col];
    if (S.act == 1) v = gelu_f(v);
    else if (S.act == 2) v *= S.scale;
    S.out[(size_t)row * S.N + c0 + col] = v;
    if (S.out2) S.out2[(size_t)row * S.N + c0 + col] = v;
    vout[cnt] = v; iout[cnt] = i; cnt++;
  }
  if (S.stats){
    __syncthreads();
    float* rf = (float*)red;
    #pragma unroll
    for (int q2 = 0; q2 < 4; q2++){
      rf[iout[q2]] = vout[q2];
      rf[1024 + iout[q2]] = vout[q2] * vout[q2];
    }
    __syncthreads();
    if (tid < 32){
      float s = 0.f, s2 = 0.f;
      #pragma unroll
      for (int cc = 0; cc < 32; cc++){ s += rf[tid * 32 + cc]; s2 += rf[1024 + tid * 32 + cc]; }
      atomicAdd(S.stats + tid, s);
      atomicAdd(S.stats + 32 + tid, s2);
    }
  }
}

__global__ __launch_bounds__(256) void linmulti_k(LinSeg s0, LinSeg s1, LinSeg s2, int n0, int n1){
  __shared__ float red[4][32][32];
  int bx = blockIdx.x, tid = threadIdx.x;
  if (bx < n0) lin_body(s0, bx, tid, red);
  else if (bx < n0 + n1) lin_body(s1, bx - n0, tid, red);
  else lin_body(s2, bx - n0 - n1, tid, red);
}

// ---------------- attention job (256 threads, fp8 K/V, unrolled) ----------------
__device__ void attn_job(int bh, int tid, const float* q, const u8* K8, const u8* V8,
                         float* afull, float* ctx0, float* shf){
  float* qs = shf;            // 64
  float* sc = shf + 64;       // 1024
  float* rr = shf + 1088;     // 8
  float* ctxp = shf + 1096;   // 16*64 = 1024
  int b = bh >> 4, h = bh & 15;
  if (tid < 64) qs[tid] = q[bh * 64 + tid];
  __syncthreads();
  const u32* kt = (const u32*)(K8 + ((size_t)(b * 1024 + h * 64)) * 1024);   // [d][s] fp8
  float a0 = 0.f, a1 = 0.f, a2 = 0.f, a3 = 0.f;
  #pragma unroll 8
  for (int d = 0; d < 64; d++){
    float qd = qs[d];
    u32 p = kt[d * 256 + tid];
    a0 += qd * dec8(p & 0xffu);
    a1 += qd * dec8((p >> 8) & 0xffu);
    a2 += qd * dec8((p >> 16) & 0xffu);
    a3 += qd * dec8(p >> 24);
  }
  float mx = fmaxf(fmaxf(a0, a1), fmaxf(a2, a3));
  for (int o = 1; o < 64; o <<= 1) mx = fmaxf(mx, __shfl_xor(mx, o));
  if ((tid & 63) == 0) rr[tid >> 6] = mx;
  __syncthreads();
  mx = fmaxf(fmaxf(rr[0], rr[1]), fmaxf(rr[2], rr[3]));
  float e0 = __expf(a0 - mx), e1 = __expf(a1 - mx), e2 = __expf(a2 - mx), e3 = __expf(a3 - mx);
  float sm = e0 + e1 + e2 + e3;
  for (int o = 1; o < 64; o <<= 1) sm += __shfl_xor(sm, o);
  if ((tid & 63) == 0) rr[4 + (tid >> 6)] = sm;
  __syncthreads();
  sm = rr[4] + rr[5] + rr[6] + rr[7];
  float inv = 1.f / sm;
  float4 wv = make_float4(e0 * inv, e1 * inv, e2 * inv, e3 * inv);
  *(float4*)(sc + 4 * tid) = wv;
  *(float4*)(afull + (size_t)bh * 1024 + 4 * tid) = wv;
  __syncthreads();
  int dd = (tid & 15) * 4, chunk = tid >> 4;      // 16 chunks x 64 s; 4 d per thread
  const u32* vp = (const u32*)(V8 + (((size_t)(b * 16 + h) * 1024 + chunk * 64) * 64 + dd));
  const float* scp = sc + chunk * 64;
  float c0 = 0.f, c1 = 0.f, c2 = 0.f, c3 = 0.f;
  #pragma unroll 8
  for (int s = 0; s < 64; s++){
    u32 vv = vp[s * 16];
    float w = scp[s];
    c0 += w * dec8(vv & 0xffu);
    c1 += w * dec8((vv >> 8) & 0xffu);
    c2 += w * dec8((vv >> 16) & 0xffu);
    c3 += w * dec8(vv >> 24);
  }
  *(float4*)(ctxp + chunk * 64 + dd) = make_float4(c0, c1, c2, c3);
  __syncthreads();
  if (tid < 64){
    float r = 0.f;
    #pragma unroll
    for (int c = 0; c < 16; c++) r += ctxp[c * 64 + tid];
    ctx0[bh * 64 + tid] = r;
  }
}

// ---------------- rule softmax + sel job (256 threads) ----------------
__device__ void rule2_job(int b, int tid, const float* h1a, const float* w2, const float* b2,
                          const float* emb, float* probs_out, float* sel, float* shf){
  float* lg = shf;        // 32
  float* psh = shf + 32;  // 32
  int j = tid >> 3, l8 = tid & 7;
  const float* xr = h1a + b * 1024;
  const float* wr = w2 + j * 1024;
  float acc = 0.f;
  #pragma unroll 8
  for (int kk = 0; kk < 32; kk++){
    int k = kk * 32 + l8 * 4;
    float4 xv = *(const float4*)(xr + k);
    float4 wv = *(const float4*)(wr + k);
    acc += xv.x * wv.x + xv.y * wv.y + xv.z * wv.z + xv.w * wv.w;
  }
  acc += __shfl_xor(acc, 1); acc += __shfl_xor(acc, 2); acc += __shfl_xor(acc, 4);
  if (l8 == 0) lg[j] = acc + b2[j];
  __syncthreads();
  if (tid < 32){
    float v = lg[tid];
    float m = v;
    for (int o = 1; o < 32; o <<= 1) m = fmaxf(m, __shfl_xor(m, o));
    float e = __expf(v - m);
    float s = e;
    for (int o = 1; o < 32; o <<= 1) s += __shfl_xor(s, o);
    float p = e / s;
    psh[tid] = p;
    probs_out[b * 32 + tid] = p;
  }
  __syncthreads();
  for (int j2 = tid; j2 < 1024; j2 += 256){
    float a2 = 0.f;
    #pragma unroll
    for (int r = 0; r < 32; r++) a2 += psh[r] * emb[r * 1024 + j2];
    sel[b * 1024 + j2] = a2;
  }
}

// ---------------- D2: attention | rule2 | LSTM1 gates | LN-stat zero (all 256-thread) ----------------
struct D2Params {
  const float* qbuf;
  const u8* K8; const u8* V8; float* afull; float* ctx0;
  const float* h1a; const float* w2; const float* b2r; const float* emb;
  float* probs_out; float* sel;
  LinSeg sL1; float* lnstats;
};
__global__ __launch_bounds__(256) void step_d2_k(D2Params P){
  __shared__ float red[4][32][32];
  float* shf = &red[0][0][0];
  int bx = blockIdx.x, tid = threadIdx.x;
  if (bx < 512){ attn_job(bx, tid, P.qbuf, P.K8, P.V8, P.afull, P.ctx0, shf); return; }
  if (bx < 544){ rule2_job(bx - 512, tid, P.h1a, P.w2, P.b2r, P.emb, P.probs_out, P.sel, shf); return; }
  if (bx < 672){ lin_body(P.sL1, bx - 544, tid, red); return; }
  if (tid < 64) P.lnstats[tid] = 0.f;
}

// ---------------- batched value head (16 steps) + verifier, grid (32, 17) ----------------
__global__ __launch_bounds__(256) void valver_k(const u16* __restrict__ vw1, const float* __restrict__ vb1,
    const u16* __restrict__ verw1, const float* __restrict__ verb1,
    const float* __restrict__ proof, float* __restrict__ v1){
  __shared__ float red[4][32][32];
  int t = blockIdx.y;
  LinSeg S = {};
  if (t < 16){
    S.X0 = proof + (size_t)t * 32768; S.K1 = 1024; S.W1 = vw1; S.ld1 = 2048; S.b1 = vb1;
    S.Y = proof + (size_t)(t + 1) * 32768; S.K2 = 1024; S.W2 = vw1 + 1024; S.ld2 = 2048;
  } else {
    S.X0 = proof + (size_t)16 * 32768; S.K1 = 1024; S.W1 = verw1; S.ld1 = 1024; S.b1 = verb1;
  }
  S.out = v1 + (size_t)t * 32768; S.N = 1024; S.act = 1;
  lin_body(S, blockIdx.x, threadIdx.x, red);
}

__global__ __launch_bounds__(256) void dotsig_b_k(const float* __restrict__ v1,
    const float* __restrict__ w2v, const float* __restrict__ b2v,
    const float* __restrict__ w2ver, const float* __restrict__ b2ver,
    float* __restrict__ out_vals, float* __restrict__ out_valid){
  int t = blockIdx.x;
  const float* w = (t < 16) ? w2v : w2ver;
  const float* bs = (t < 16) ? b2v : b2ver;
  const float* x = v1 + (size_t)t * 32768;
  int b = threadIdx.x >> 3, l8 = threadIdx.x & 7;
  const float* xr = x + (size_t)b * 1024;
  float acc = 0.f;
  #pragma unroll 8
  for (int kk = 0; kk < 32; kk++){
    int k = kk * 32 + l8 * 4;
    float4 xv = *(const float4*)(xr + k);
    float4 wv = *(const float4*)(w + k);
    acc += xv.x * wv.x + xv.y * wv.y + xv.z * wv.z + xv.w * wv.w;
  }
  acc += __shfl_xor(acc, 1); acc += __shfl_xor(acc, 2); acc += __shfl_xor(acc, 4);
  if (l8 == 0){
    float r = sigm_f(acc + bs[0]);
    if (t < 16) out_vals[t * 32 + b] = r; else out_valid[b] = r;
  }
}

// ---------------- batched attn head-mean over all 16 steps ----------------
__global__ __launch_bounds__(256) void attnavg_all_k(const float* __restrict__ afull, float* __restrict__ out){
  int idx = blockIdx.x * 256 + threadIdx.x;     // 16*32768
  int t = idx >> 15, r = idx & 32767;
  int b = r >> 10, s = r & 1023;
  const float* base = afull + (size_t)t * 524288 + (size_t)b * 16384;
  float acc = 0.f;
  #pragma unroll
  for (int h = 0; h < 16; h++) acc += base[h * 1024 + s];
  out[idx] = acc * (1.f / 16.f);
}

extern "C" void kernel_launch(void* const* d_in, const int* in_sizes, int n_in,
                              void* d_out, int out_size, void* d_ws, size_t ws_size,
                              hipStream_t stream) {
  const float* comp      = (const float*)d_in[0];
  const float* rule_w1   = (const float*)d_in[2];
  const float* rule_b1   = (const float*)d_in[3];
  const float* rule_w2   = (const float*)d_in[4];
  const float* rule_b2   = (const float*)d_in[5];
  const float* rule_emb  = (const float*)d_in[6];
  const float* attn_in_w = (const float*)d_in[7];
  const float* attn_in_b = (const float*)d_in[8];
  const float* attn_out_w= (const float*)d_in[9];
  const float* attn_out_b= (const float*)d_in[10];
  const float* wih0 = (const float*)d_in[11];
  const float* whh0 = (const float*)d_in[12];
  const float* bih0 = (const float*)d_in[13];
  const float* bhh0 = (const float*)d_in[14];
  const float* wih1 = (const float*)d_in[15];
  const float* whh1 = (const float*)d_in[16];
  const float* bih1 = (const float*)d_in[17];
  const float* bhh1 = (const float*)d_in[18];
  const float* gen_w1 = (const float*)d_in[19];
  const float* gen_b1 = (const float*)d_in[20];
  const float* ln_g   = (const float*)d_in[21];
  const float* ln_b   = (const float*)d_in[22];
  const float* gen_w2 = (const float*)d_in[23];
  const float* gen_b2 = (const float*)d_in[24];
  const float* val_w1 = (const float*)d_in[25];
  const float* val_b1 = (const float*)d_in[26];
  const float* val_w2 = (const float*)d_in[27];
  const float* val_b2 = (const float*)d_in[28];
  const float* ver_w1 = (const float*)d_in[29];
  const float* ver_b1 = (const float*)d_in[30];
  const float* ver_w2 = (const float*)d_in[31];
  const float* ver_b2 = (const float*)d_in[32];

  float* out_f     = (float*)d_out;
  float* out_proof = out_f;                       // (17,32,1024)
  float* out_valid = out_f + 17 * 32768;          // (32,1)
  float* out_probs = out_valid + 32;              // (16,32,32)
  float* out_vals  = out_probs + 16 * 1024;       // (16,32,1)
  float* out_attn  = out_vals + 16 * 32;          // (16,32,1024)

  char* wp = (char*)d_ws;
  auto carve = [&](size_t bytes) -> void* {
    void* p = (void*)wp; wp += (bytes + 255) & ~(size_t)255; return p;
  };
  u8* K8     = (u8*)carve((size_t)33554432);        // fp8 [b][hd][s]
  u8* V8     = (u8*)carve((size_t)33554432);        // fp8 [b][h][s][d]
  u16* compb = (u16*)carve((size_t)33554432 * 2);   // bf16 comp; afull_all aliases after gemms
  float* afull_all = (float*)compb;                 // 16 * 512 * 1024 fp32 = 32MB
  u16* rw1b  = (u16*)carve(2097152);
  u16* wqb   = (u16*)carve(2097152);
  u16* wkb   = (u16*)carve(2097152);
  u16* wvb   = (u16*)carve(2097152);
  u16* aowTb = (u16*)carve(2097152);                // attn_out_w^T bf16
  u16* wih0b = (u16*)carve(8388608);
  u16* whh0b = (u16*)carve(8388608);
  u16* wih1b = (u16*)carve(8388608);
  u16* whh1b = (u16*)carve(8388608);
  u16* gw1b  = (u16*)carve(4194304);
  u16* gw2b  = (u16*)carve(4194304);
  u16* vw1b  = (u16*)carve(4194304);
  u16* verw1b= (u16*)carve(2097152);
  u16* gaw   = (u16*)carve(4194304);                // gw1 @ aow, [2048,1024] bf16
  float* bias2 = (float*)carve(8192);               // gen_b1 + gw1@aob
  float* psb[2]  = { (float*)carve(131072), (float*)carve(131072) };
  float* h0b[2]  = { (float*)carve(131072), (float*)carve(131072) };
  float* c0b[2]  = { (float*)carve(131072), (float*)carve(131072) };
  float* h1b[2]  = { (float*)carve(131072), (float*)carve(131072) };
  float* c1b[2]  = { (float*)carve(131072), (float*)carve(131072) };
  float* h1act = (float*)carve(131072);
  float* sel   = (float*)carve(131072);
  float* qbuf  = (float*)carve(131072);
  float* ctx0  = (float*)carve(131072);
  float* zbuf  = (float*)carve(262144);
  float* v1buf = (float*)carve(2228224);            // 17 * 32768 fp32
  float* lnstats = (float*)carve(256);
  (void)ws_size; (void)in_sizes; (void)n_in; (void)out_size;

  // ---- weight casts + transpose-cast + comp cast ----
  CastJobs J;
  const float* srcs[12] = { rule_w1, attn_in_w, attn_in_w + 1048576, attn_in_w + 2097152,
                            wih0, whh0, wih1, whh1, gen_w1, gen_w2, val_w1, ver_w1 };
  u16* dsts[12] = { rw1b, wqb, wkb, wvb, wih0b, whh0b, wih1b, whh1b, gw1b, gw2b, vw1b, verw1b };
  int sizes[12] = { 1048576, 1048576, 1048576, 1048576,
                    4194304, 4194304, 4194304, 4194304, 2097152, 2097152, 2097152, 1048576 };
  int st = 0;
  for (int i = 0; i < 12; i++){ J.s[i] = srcs[i]; J.d[i] = dsts[i]; J.start[i] = st; st += sizes[i] / 1024; }
  J.start[12] = st;
  cast_all_k<<<dim3(st), dim3(256), 0, stream>>>(J);
  tcast_k<<<dim3(1024), dim3(256), 0, stream>>>(attn_out_w, aowTb);
  cast_k<<<dim3(32768), dim3(256), 0, stream>>>(comp, compb, 33554432);

  gemmkv_k<<<dim3(2048, 1, 2), dim3(256), 0, stream>>>(compb, wkb, wvb,
      attn_in_b + 1024, attn_in_b + 2048, K8, V8);
  gemmbb_k<<<dim3(16, 8), dim3(256), 0, stream>>>(gw1b, aowTb, gaw);
  bias2_k<<<dim3(64), dim3(256), 0, stream>>>(gen_w1, attn_out_b, gen_b1, bias2);

  init_k<<<dim3(128), dim3(256), 0, stream>>>(comp, psb[0], out_proof,
      h0b[0], c0b[0], h1b[0], c1b[0]);

  for (int t = 0; t < 16; t++){
    int cur = t & 1, nx = cur ^ 1;
    float* ps = psb[cur];
    float* afull_t = afull_all + (size_t)t * 524288;
    // D1: rule h1 (gelu, 32) + q (scaled, 32) + LSTM0 complete (128 gate tiles)
    LinSeg sRule = {}; sRule.X0 = ps; sRule.K1 = 1024; sRule.W1 = rw1b; sRule.ld1 = 1024;
    sRule.b1 = rule_b1; sRule.out = h1act; sRule.N = 1024; sRule.act = 1;
    LinSeg sQ = {}; sQ.X0 = ps; sQ.K1 = 1024; sQ.W1 = wqb; sQ.ld1 = 1024; sQ.b1 = attn_in_b;
    sQ.out = qbuf; sQ.N = 1024; sQ.act = 2; sQ.scale = 0.125f;
    LinSeg sL0 = {}; sL0.X0 = ps; sL0.K1 = 1024; sL0.W1 = wih0b; sL0.ld1 = 1024; sL0.b1 = bih0;
    sL0.Y = h0b[cur]; sL0.K2 = 1024; sL0.W2 = whh0b; sL0.ld2 = 1024; sL0.b2 = bhh0;
    sL0.gate = 1; sL0.cprev = c0b[cur]; sL0.cout = c0b[nx]; sL0.hout = h0b[nx];
    linmulti_k<<<dim3(192), dim3(256), 0, stream>>>(sRule, sQ, sL0, 32, 32);
    // D2: attention + rule2 + LSTM1 complete + LN-stat zero
    D2Params P;
    P.qbuf = qbuf;
    P.K8 = K8; P.V8 = V8; P.afull = afull_t; P.ctx0 = ctx0;
    P.h1a = h1act; P.w2 = rule_w2; P.b2r = rule_b2; P.emb = rule_emb;
    P.probs_out = out_probs + t * 1024; P.sel = sel;
    LinSeg sL1 = {}; sL1.X0 = h0b[nx]; sL1.K1 = 1024; sL1.W1 = wih1b; sL1.ld1 = 1024; sL1.b1 = bih1;
    sL1.Y = h1b[cur]; sL1.K2 = 1024; sL1.W2 = whh1b; sL1.ld2 = 1024; sL1.b2 = bhh1;
    sL1.gate = 1; sL1.cprev = c1b[cur]; sL1.cout = c1b[nx]; sL1.hout = h1b[nx];
    P.sL1 = sL1; P.lnstats = lnstats;
    step_d2_k<<<dim3(673), dim3(256), 0, stream>>>(P);
    // D3: z = (ps+sel+mem)@gw1^T + ctx0@gaw^T + bias2, with LN-stat accumulation
    LinSeg sG1 = {}; sG1.X0 = ps; sG1.Xa = sel; sG1.Xb = h1b[nx];
    sG1.K1 = 1024; sG1.W1 = gw1b; sG1.ld1 = 1024; sG1.b1 = bias2;
    sG1.Y = ctx0; sG1.K2 = 1024; sG1.W2 = gaw; sG1.ld2 = 1024;
    sG1.out = zbuf; sG1.N = 2048; sG1.stats = lnstats;
    linmulti_k<<<dim3(64), dim3(256), 0, stream>>>(sG1, sG1, sG1, 64, 0);
    // D4: nxt = gelu(LN(z)) @ gw2^T + b
    LinSeg sG2 = {}; sG2.X0 = zbuf; sG2.K1 = 2048; sG2.W1 = gw2b; sG2.ld1 = 2048; sG2.b1 = gen_b2;
    sG2.out = psb[nx]; sG2.N = 1024; sG2.out2 = out_proof + (size_t)(t + 1) * 32768;
    sG2.lng = ln_g; sG2.lnb = ln_b; sG2.lnstats = lnstats;
    linmulti_k<<<dim3(32), dim3(256), 0, stream>>>(sG2, sG2, sG2, 32, 0);
  }
  // post-loop: batched value heads (16) + verifier (grid.y = 17)
  valver_k<<<dim3(32, 17), dim3(256), 0, stream>>>(vw1b, val_b1, verw1b, ver_b1, out_proof, v1buf);
  dotsig_b_k<<<dim3(17), dim3(256), 0, stream>>>(v1buf, val_w2, val_b2, ver_w2, ver_b2,
      out_vals, out_valid);
  attnavg_all_k<<<dim3(2048), dim3(256), 0, stream>>>(afull_all, out_attn);
}

// Round 10
// 2018.537 us; speedup vs baseline: 1.0490x; 1.0490x over previous
//
#include <hip/hip_runtime.h>

typedef unsigned short u16;
typedef unsigned int u32;
typedef __attribute__((ext_vector_type(8))) short short8v;   // 8 bf16 (4 VGPRs)
typedef __attribute__((ext_vector_type(4))) float f32x4;

#define MFMA16(a,b,c) __builtin_amdgcn_mfma_f32_16x16x32_bf16((a),(b),(c),0,0,0)

__device__ __forceinline__ u16 f2bf(float f){
  u32 u = __float_as_uint(f);
  return (u16)((u + 0x7fffu + ((u >> 16) & 1u)) >> 16);   // RNE
}
__device__ __forceinline__ float bf2f(u16 h){ return __uint_as_float(((u32)h) << 16); }
__device__ __forceinline__ float gelu_f(float x){ return 0.5f * x * (1.f + erff(x * 0.70710678118654752f)); }
__device__ __forceinline__ float sigm_f(float x){ return 1.f / (1.f + __expf(-x)); }
__device__ __forceinline__ void acc4(float4& a, const float4 b){ a.x+=b.x; a.y+=b.y; a.z+=b.z; a.w+=b.w; }

// async global->LDS, 16B per lane
__device__ __forceinline__ void gl16(const void* g, void* l){
  __builtin_amdgcn_global_load_lds((const __attribute__((address_space(1))) u32*)g,
                                   (__attribute__((address_space(3))) u32*)l, 16, 0, 0);
}

// ---------------- fused cast fp32 -> bf16 (13 jobs incl comp, one launch) ----------------
struct CastJobs { const float* s[13]; u16* d[13]; int start[14]; };
__global__ __launch_bounds__(256) void cast_all_k(CastJobs J){
  int bx = blockIdx.x, j = 0;
  #pragma unroll
  for (int t = 0; t < 13; t++) if (bx >= J.start[t + 1]) j = t + 1;
  int i = (bx - J.start[j]) * 1024 + threadIdx.x * 4;
  float4 v = *(const float4*)(J.s[j] + i);
  ushort4 o; o.x = f2bf(v.x); o.y = f2bf(v.y); o.z = f2bf(v.z); o.w = f2bf(v.w);
  *(ushort4*)(J.d[j] + i) = o;
}

// ---------------- transpose-cast 1024x1024 fp32 -> bf16^T ----------------
__global__ __launch_bounds__(256) void tcast_k(const float* __restrict__ s, u16* __restrict__ d){
  __shared__ float tile[32][33];
  int bx = blockIdx.x & 31, by = blockIdx.x >> 5;
  int tx = threadIdx.x & 31, ty = threadIdx.x >> 5;
  #pragma unroll
  for (int i = 0; i < 4; i++)
    tile[ty + i * 8][tx] = s[(size_t)(by * 32 + ty + i * 8) * 1024 + bx * 32 + tx];
  __syncthreads();
  #pragma unroll
  for (int i = 0; i < 4; i++)
    d[(size_t)(bx * 32 + ty + i * 8) * 1024 + by * 32 + tx] = f2bf(tile[tx][ty + i * 8]);
}

// ---------------- bias2 = gen_b1 + gw1 @ aob ----------------
__global__ __launch_bounds__(256) void bias2_k(const float* __restrict__ gw1, const float* __restrict__ aob,
                                               const float* __restrict__ gb1, float* __restrict__ out){
  int j = blockIdx.x * 32 + (threadIdx.x >> 3);
  int l8 = threadIdx.x & 7;
  const float* r = gw1 + (size_t)j * 1024;
  float acc = 0.f;
  #pragma unroll 8
  for (int kk = 0; kk < 32; kk++){
    int k = kk * 32 + l8 * 4;
    float4 a = *(const float4*)(r + k);
    float4 w = *(const float4*)(aob + k);
    acc += a.x * w.x + a.y * w.y + a.z * w.z + a.w * w.w;
  }
  acc += __shfl_xor(acc, 1); acc += __shfl_xor(acc, 2); acc += __shfl_xor(acc, 4);
  if (l8 == 0) out[j] = gb1[j] + acc;
}

// ---------------- init: ps partials, zero states ----------------
__global__ __launch_bounds__(256) void init_k(const float* __restrict__ comp, float* psa, float* psbz,
                                              float* outp, float* h0, float* c0, float* h1, float* c1){
  int i = blockIdx.x * 256 + threadIdx.x;       // 32768
  int b = i >> 10, hh = i & 1023;
  float v = comp[(size_t)b * 1048576 + hh];
  psa[i] = v; psbz[i] = 0.f; outp[i] = v;
  h0[i] = 0.f; c0[i] = 0.f; h1[i] = 0.f; c1[i] = 0.f;
}

// ---------------- fused K/V GEMM (bf16 out). Kt:[b][hd][s], Vb:[b][h][s][d] ----------------
__global__ __launch_bounds__(256) void gemmkv_k(const u16* __restrict__ compb,
    const u16* __restrict__ Wk, const u16* __restrict__ Wv,
    const float* __restrict__ bk, const float* __restrict__ bv,
    u16* __restrict__ Kt, u16* __restrict__ Vb)
{
  __shared__ u16 Sh[16384];               // As(16KB)+Bs(16KB); reused as C-tile
  u16* As = Sh;
  u16* Bs = Sh + 8192;
  int tid = threadIdx.x;
  int x = blockIdx.x;
  int xcd = x & 7, p = x >> 3;
  int cpanel = xcd * 32 + (p >> 3);
  int wpanel = p & 7;
  int isK = (blockIdx.z != 0);
  const u16 *msrc, *nsrc; int m0, n0;
  if (!isK){ m0 = cpanel * 128; n0 = wpanel * 128; msrc = compb; nsrc = Wv; }
  else     { m0 = wpanel * 128; n0 = cpanel * 128; msrc = Wk;    nsrc = compb; }

  int w = tid >> 6, l = tid & 63, lr = l & 15, lk = l >> 4;
  int wm = (w >> 1) * 64, wn = (w & 1) * 64;
  f32x4 acc[4][4];
  #pragma unroll
  for (int i = 0; i < 4; i++)
    #pragma unroll
    for (int j = 0; j < 4; j++) acc[i][j] = (f32x4){0.f,0.f,0.f,0.f};

  for (int kc = 0; kc < 1024; kc += 64){
    #pragma unroll
    for (int r = 0; r < 4; r++){
      int s = tid + r * 256;
      int row = s >> 3, pp = s & 7;
      int lg = pp ^ (row & 7);
      gl16(msrc + (size_t)(m0 + row) * 1024 + kc + lg * 8, As + s * 8);
      gl16(nsrc + (size_t)(n0 + row) * 1024 + kc + lg * 8, Bs + s * 8);
    }
    __syncthreads();
    #pragma unroll
    for (int kk = 0; kk < 2; kk++){
      short8v a[4], bb[4];
      #pragma unroll
      for (int mi = 0; mi < 4; mi++){
        int row = wm + mi * 16 + lr;
        int ph = (kk * 4 + lk) ^ (row & 7);
        a[mi] = *(const short8v*)(As + row * 64 + ph * 8);
      }
      #pragma unroll
      for (int ni = 0; ni < 4; ni++){
        int row = wn + ni * 16 + lr;
        int ph = (kk * 4 + lk) ^ (row & 7);
        bb[ni] = *(const short8v*)(Bs + row * 64 + ph * 8);
      }
      #pragma unroll
      for (int mi = 0; mi < 4; mi++)
        #pragma unroll
        for (int ni = 0; ni < 4; ni++)
          acc[mi][ni] = MFMA16(a[mi], bb[ni], acc[mi][ni]);
    }
    __syncthreads();
  }
  #pragma unroll
  for (int mi = 0; mi < 4; mi++)
    #pragma unroll
    for (int ni = 0; ni < 4; ni++)
      #pragma unroll
      for (int r = 0; r < 4; r++){
        int row = wm + mi * 16 + lk * 4 + r;
        int col = wn + ni * 16 + lr;
        float bias = isK ? bk[m0 + row] : bv[n0 + col];
        Sh[row * 128 + col] = f2bf(acc[mi][ni][r] + bias);
      }
  __syncthreads();
  for (int i = tid; i < 2048; i += 256){
    int r = i >> 4, c8 = (i & 15) * 8;
    uint4 o = *(const uint4*)(Sh + r * 128 + c8);
    if (!isK){
      int bs = m0 + r, hd = n0 + c8;
      int b = bs >> 10, s = bs & 1023;
      int h = hd >> 6, d = hd & 63;
      *(uint4*)(Vb + ((size_t)(b * 16 + h) * 1024 + s) * 64 + d) = o;
    } else {
      int hd = m0 + r, bs = n0 + c8;
      int b = bs >> 10, s = bs & 1023;
      *(uint4*)(Kt + ((size_t)b * 1024 + hd) * 1024 + s) = o;
    }
  }
}

// ---------------- gaw = gw1 @ aow ----------------
__global__ __launch_bounds__(256) void gemmbb_k(const u16* __restrict__ A, const u16* __restrict__ B,
                                                u16* __restrict__ C)
{
  __shared__ u16 As[128 * 64];
  __shared__ u16 Bs[128 * 64];
  int tid = threadIdx.x;
  int m0 = blockIdx.x * 128, n0 = blockIdx.y * 128;
  int w = tid >> 6, l = tid & 63, lr = l & 15, lk = l >> 4;
  int wm = (w >> 1) * 64, wn = (w & 1) * 64;
  f32x4 acc[4][4];
  #pragma unroll
  for (int i = 0; i < 4; i++)
    #pragma unroll
    for (int j = 0; j < 4; j++) acc[i][j] = (f32x4){0.f,0.f,0.f,0.f};
  for (int kc = 0; kc < 1024; kc += 64){
    #pragma unroll
    for (int r = 0; r < 4; r++){
      int s = tid + r * 256;
      int row = s >> 3, pp = s & 7;
      int lg = pp ^ (row & 7);
      gl16(A + (size_t)(m0 + row) * 1024 + kc + lg * 8, As + s * 8);
      gl16(B + (size_t)(n0 + row) * 1024 + kc + lg * 8, Bs + s * 8);
    }
    __syncthreads();
    #pragma unroll
    for (int kk = 0; kk < 2; kk++){
      short8v a[4], bb[4];
      #pragma unroll
      for (int mi = 0; mi < 4; mi++){
        int row = wm + mi * 16 + lr;
        int ph = (kk * 4 + lk) ^ (row & 7);
        a[mi] = *(const short8v*)(As + row * 64 + ph * 8);
      }
      #pragma unroll
      for (int ni = 0; ni < 4; ni++){
        int row = wn + ni * 16 + lr;
        int ph = (kk * 4 + lk) ^ (row & 7);
        bb[ni] = *(const short8v*)(Bs + row * 64 + ph * 8);
      }
      #pragma unroll
      for (int mi = 0; mi < 4; mi++)
        #pragma unroll
        for (int ni = 0; ni < 4; ni++)
          acc[mi][ni] = MFMA16(a[mi], bb[ni], acc[mi][ni]);
    }
    __syncthreads();
  }
  #pragma unroll
  for (int mi = 0; mi < 4; mi++)
    #pragma unroll
    for (int ni = 0; ni < 4; ni++)
      #pragma unroll
      for (int r = 0; r < 4; r++){
        int row = m0 + wm + mi * 16 + lk * 4 + r;
        int col = n0 + wn + ni * 16 + lr;
        C[(size_t)row * 1024 + col] = f2bf(acc[mi][ni][r]);
      }
}

// ---------------- M=32, N=16 MFMA linear tile (256 threads / 4 waves, 8KB red) ----------------
struct LinSeg {
  const float* X0; const float* Xa; const float* Xb; const float* Xc;
  const u16* W1; const float* b1;
  const float* Y; const u16* W2; const float* b2;
  float* out; float* out2;
  int K1, ldx, ld1, K2, ld2, N, act, gate;   // ldx: A row stride; act 0/1 gelu/2 scale
  float scale;
  float* stats;
  const float* lng; const float* lnb; const float* lnstats;
  const float* cprev; float* cout; float* hout;
};

__device__ __forceinline__ short8v pack8(float4 v0, float4 v1){
  short8v r;
  r[0]=(short)f2bf(v0.x); r[1]=(short)f2bf(v0.y); r[2]=(short)f2bf(v0.z); r[3]=(short)f2bf(v0.w);
  r[4]=(short)f2bf(v1.x); r[5]=(short)f2bf(v1.y); r[6]=(short)f2bf(v1.z); r[7]=(short)f2bf(v1.w);
  return r;
}

__device__ __forceinline__ short8v load_sum8(const LinSeg& S, int row, int kb){
  size_t o = (size_t)row * S.ldx + kb;
  float4 v0 = *(const float4*)(S.X0 + o);
  float4 v1 = *(const float4*)(S.X0 + o + 4);
  if (S.lng){
    float mu = S.lnstats[row] * (1.f / 2048.f);
    float ms = S.lnstats[32 + row] * (1.f / 2048.f);
    float rstd = rsqrtf(ms - mu * mu + 1e-5f);
    float4 g0 = *(const float4*)(S.lng + kb), g1 = *(const float4*)(S.lng + kb + 4);
    float4 b0 = *(const float4*)(S.lnb + kb), b1 = *(const float4*)(S.lnb + kb + 4);
    v0.x = gelu_f((v0.x - mu) * rstd * g0.x + b0.x);
    v0.y = gelu_f((v0.y - mu) * rstd * g0.y + b0.y);
    v0.z = gelu_f((v0.z - mu) * rstd * g0.z + b0.z);
    v0.w = gelu_f((v0.w - mu) * rstd * g0.w + b0.w);
    v1.x = gelu_f((v1.x - mu) * rstd * g1.x + b1.x);
    v1.y = gelu_f((v1.y - mu) * rstd * g1.y + b1.y);
    v1.z = gelu_f((v1.z - mu) * rstd * g1.z + b1.z);
    v1.w = gelu_f((v1.w - mu) * rstd * g1.w + b1.w);
  } else {
    if (S.Xa){ acc4(v0, *(const float4*)(S.Xa + o)); acc4(v1, *(const float4*)(S.Xa + o + 4)); }
    if (S.Xb){ acc4(v0, *(const float4*)(S.Xb + o)); acc4(v1, *(const float4*)(S.Xb + o + 4)); }
    if (S.Xc){ acc4(v0, *(const float4*)(S.Xc + o)); acc4(v1, *(const float4*)(S.Xc + o + 4)); }
  }
  return pack8(v0, v1);
}
__device__ __forceinline__ short8v load_y8(const float* p){
  return pack8(*(const float4*)(p), *(const float4*)(p + 4));
}

typedef float Red16[32][16];   // red[4][32][16] = 8KB

__device__ void lin_body(const LinSeg& S, int bi, int tid, Red16* red){
  int c0 = bi * 16, j0 = bi * 4;
  int w = tid >> 6, l = tid & 63, lr = l & 15, lk = l >> 4;
  int wc0 = S.gate ? ((lr >> 2) << 10) + j0 + (lr & 3) : c0 + lr;
  f32x4 acc[2];
  acc[0] = (f32x4){0.f,0.f,0.f,0.f};
  acc[1] = (f32x4){0.f,0.f,0.f,0.f};

  {
    int chunk = S.K1 >> 2;
    int kb0 = w * chunk + lk * 8;
    for (int kk = 0; kk < chunk; kk += 32){
      int kb = kb0 + kk;
      short8v a0 = load_sum8(S, lr, kb);
      short8v a1 = load_sum8(S, lr + 16, kb);
      short8v w0 = *(const short8v*)(S.W1 + (size_t)wc0 * S.ld1 + kb);
      acc[0] = MFMA16(a0, w0, acc[0]);
      acc[1] = MFMA16(a1, w0, acc[1]);
    }
  }
  if (S.Y){
    int chunk = S.K2 >> 2;
    int kb0 = w * chunk + lk * 8;
    for (int kk = 0; kk < chunk; kk += 32){
      int kb = kb0 + kk;
      short8v a0 = load_y8(S.Y + (size_t)lr * S.K2 + kb);
      short8v a1 = load_y8(S.Y + (size_t)(lr + 16) * S.K2 + kb);
      short8v w0 = *(const short8v*)(S.W2 + (size_t)wc0 * S.ld2 + kb);
      acc[0] = MFMA16(a0, w0, acc[0]);
      acc[1] = MFMA16(a1, w0, acc[1]);
    }
  }
  #pragma unroll
  for (int mi = 0; mi < 2; mi++)
    #pragma unroll
    for (int r = 0; r < 4; r++)
      red[w][mi * 16 + lk * 4 + r][lr] = acc[mi][r];
  __syncthreads();
  if (S.gate){
    if (tid < 128){
      int row = tid >> 2, j = tid & 3;
      float s[4];
      #pragma unroll
      for (int g = 0; g < 4; g++){
        float v = 0.f;
        #pragma unroll
        for (int ww = 0; ww < 4; ww++) v += red[ww][row][g * 4 + j];
        s[g] = v;
      }
      int gc = j0 + j;
      float gI = s[0] + S.b1[gc]        + S.b2[gc];
      float gF = s[1] + S.b1[1024 + gc] + S.b2[1024 + gc];
      float gG = s[2] + S.b1[2048 + gc] + S.b2[2048 + gc];
      float gO = s[3] + S.b1[3072 + gc] + S.b2[3072 + gc];
      int idx = row * 1024 + gc;
      float cN = sigm_f(gF) * S.cprev[idx] + sigm_f(gI) * tanhf(gG);
      S.cout[idx] = cN;
      S.hout[idx] = sigm_f(gO) * tanhf(cN);
    }
    return;
  }
  float vout[2]; int iout[2];
  int cnt = 0;
  for (int i = tid; i < 512; i += 256){
    int row = i >> 4, col = i & 15;
    float v = 0.f;
    #pragma unroll
    for (int ww = 0; ww < 4; ww++) v += red[ww][row][col];
    if (S.b1) v += S.b1[c0 + col];
    if (S.b2) v += S.b2[c0 + col];
    if (S.act == 1) v = gelu_f(v);
    else if (S.act == 2) v *= S.scale;
    S.out[(size_t)row * S.N + c0 + col] = v;
    if (S.out2) S.out2[(size_t)row * S.N + c0 + col] = v;
    vout[cnt] = v; iout[cnt] = i; cnt++;
  }
  if (S.stats){
    __syncthreads();
    float* rf = (float*)red;
    rf[iout[0]] = vout[0]; rf[512 + iout[0]] = vout[0] * vout[0];
    rf[iout[1]] = vout[1]; rf[512 + iout[1]] = vout[1] * vout[1];
    __syncthreads();
    if (tid < 32){
      float s = 0.f, s2 = 0.f;
      #pragma unroll
      for (int cc = 0; cc < 16; cc++){ s += rf[tid * 16 + cc]; s2 += rf[512 + tid * 16 + cc]; }
      atomicAdd(S.stats + tid, s);
      atomicAdd(S.stats + 32 + tid, s2);
    }
  }
}

__global__ __launch_bounds__(256) void linmulti_k(LinSeg s0, LinSeg s1, LinSeg s2, int n0, int n1){
  __shared__ float red[4][32][16];
  int bx = blockIdx.x, tid = threadIdx.x;
  if (bx < n0) lin_body(s0, bx, tid, red);
  else if (bx < n0 + n1) lin_body(s1, bx - n0, tid, red);
  else lin_body(s2, bx - n0 - n1, tid, red);
}

// ---------------- attention job (256 threads, bf16 K/V, unroll 8) ----------------
__device__ void attn_job(int bh, int tid, const float* q, const u16* Kt, const u16* Vb,
                         float* afull, float* ctx0, float* shf){
  float* qs = shf;            // 64
  float* sc = shf + 64;       // 1024
  float* rr = shf + 1088;     // 8
  float* ctxp = shf + 1096;   // 8*64 = 512
  int b = bh >> 4, h = bh & 15;
  if (tid < 64) qs[tid] = q[bh * 64 + tid];
  __syncthreads();
  const u32* kt = (const u32*)(Kt + (size_t)bh * 65536);   // [d][s/2]
  float a0 = 0.f, a1 = 0.f, a2 = 0.f, a3 = 0.f;
  #pragma unroll 8
  for (int d = 0; d < 64; d++){
    float qd = qs[d];
    u32 p0 = kt[d * 512 + tid];
    u32 p1 = kt[d * 512 + tid + 256];
    a0 += qd * bf2f((u16)(p0 & 0xffff)); a1 += qd * bf2f((u16)(p0 >> 16));
    a2 += qd * bf2f((u16)(p1 & 0xffff)); a3 += qd * bf2f((u16)(p1 >> 16));
  }
  float mx = fmaxf(fmaxf(a0, a1), fmaxf(a2, a3));
  for (int o = 1; o < 64; o <<= 1) mx = fmaxf(mx, __shfl_xor(mx, o));
  if ((tid & 63) == 0) rr[tid >> 6] = mx;
  __syncthreads();
  mx = fmaxf(fmaxf(rr[0], rr[1]), fmaxf(rr[2], rr[3]));
  float e0 = __expf(a0 - mx), e1 = __expf(a1 - mx), e2 = __expf(a2 - mx), e3 = __expf(a3 - mx);
  float sm = e0 + e1 + e2 + e3;
  for (int o = 1; o < 64; o <<= 1) sm += __shfl_xor(sm, o);
  if ((tid & 63) == 0) rr[4 + (tid >> 6)] = sm;
  __syncthreads();
  sm = rr[4] + rr[5] + rr[6] + rr[7];
  float inv = 1.f / sm;
  float* ar = afull + (size_t)bh * 1024;
  float2 w0 = make_float2(e0 * inv, e1 * inv);
  float2 w1 = make_float2(e2 * inv, e3 * inv);
  *(float2*)(sc + 2 * tid) = w0;       *(float2*)(ar + 2 * tid) = w0;
  *(float2*)(sc + 512 + 2 * tid) = w1; *(float2*)(ar + 512 + 2 * tid) = w1;
  __syncthreads();
  int dd2 = tid & 31, chunk = tid >> 5;             // 8 chunks x 128 s; 2 d per thread
  const u32* vp = (const u32*)(Vb + ((size_t)(b * 16 + h) * 1024 + chunk * 128) * 64) + dd2;
  const float* scp = sc + chunk * 128;
  float c0 = 0.f, c1 = 0.f;
  #pragma unroll 8
  for (int s = 0; s < 128; s++){
    u32 vv = vp[s * 32];
    float w = scp[s];
    c0 += w * bf2f((u16)(vv & 0xffff));
    c1 += w * bf2f((u16)(vv >> 16));
  }
  *(float2*)(ctxp + chunk * 64 + dd2 * 2) = make_float2(c0, c1);
  __syncthreads();
  if (tid < 64){
    float r = 0.f;
    #pragma unroll
    for (int c = 0; c < 8; c++) r += ctxp[c * 64 + tid];
    ctx0[bh * 64 + tid] = r;
  }
}

// ---------------- rule softmax + sel job ----------------
__device__ void rule2_job(int b, int tid, const float* h1a, const float* w2, const float* b2,
                          const float* emb, float* probs_out, float* sel, float* shf){
  float* lg = shf;
  float* psh = shf + 32;
  int j = tid >> 3, l8 = tid & 7;
  const float* xr = h1a + b * 1024;
  const float* wr = w2 + j * 1024;
  float acc = 0.f;
  #pragma unroll 8
  for (int kk = 0; kk < 32; kk++){
    int k = kk * 32 + l8 * 4;
    float4 xv = *(const float4*)(xr + k);
    float4 wv = *(const float4*)(wr + k);
    acc += xv.x * wv.x + xv.y * wv.y + xv.z * wv.z + xv.w * wv.w;
  }
  acc += __shfl_xor(acc, 1); acc += __shfl_xor(acc, 2); acc += __shfl_xor(acc, 4);
  if (l8 == 0) lg[j] = acc + b2[j];
  __syncthreads();
  if (tid < 32){
    float v = lg[tid];
    float m = v;
    for (int o = 1; o < 32; o <<= 1) m = fmaxf(m, __shfl_xor(m, o));
    float e = __expf(v - m);
    float s = e;
    for (int o = 1; o < 32; o <<= 1) s += __shfl_xor(s, o);
    float p = e / s;
    psh[tid] = p;
    probs_out[b * 32 + tid] = p;
  }
  __syncthreads();
  for (int j2 = tid; j2 < 1024; j2 += 256){
    float a2 = 0.f;
    #pragma unroll
    for (int r = 0; r < 32; r++) a2 += psh[r] * emb[r * 1024 + j2];
    sel[b * 1024 + j2] = a2;
  }
}

// ---------------- D1: rule(64) | q(64) | lstm0(256) | proof-fixup(32) ----------------
__global__ __launch_bounds__(256) void step_d1_k(LinSeg sRule, LinSeg sQ, LinSeg sL0,
                                                 const float* pa, const float* pb, float* proof_t){
  __shared__ float red[4][32][16];
  int bx = blockIdx.x, tid = threadIdx.x;
  if (bx < 64){ lin_body(sRule, bx, tid, red); return; }
  if (bx < 128){ lin_body(sQ, bx - 64, tid, red); return; }
  if (bx < 384){ lin_body(sL0, bx - 128, tid, red); return; }
  int i = (bx - 384) * 1024 + tid * 4;
  float4 va = *(const float4*)(pa + i);
  float4 vb = *(const float4*)(pb + i);
  acc4(va, vb);
  *(float4*)(proof_t + i) = va;
}

// ---------------- D2: attention(512) | rule2(32) | lstm1(256) | LN-zero(1) ----------------
struct D2Params {
  const float* qbuf;
  const u16* Kt; const u16* Vb; float* afull; float* ctx0;
  const float* h1a; const float* w2; const float* b2r; const float* emb;
  float* probs_out; float* sel;
  LinSeg sL1; float* lnstats;
};
__global__ __launch_bounds__(256) void step_d2_k(D2Params P){
  __shared__ float red[4][32][16];
  float* shf = &red[0][0][0];
  int bx = blockIdx.x, tid = threadIdx.x;
  if (bx < 512){ attn_job(bx, tid, P.qbuf, P.Kt, P.Vb, P.afull, P.ctx0, shf); return; }
  if (bx < 544){ rule2_job(bx - 512, tid, P.h1a, P.w2, P.b2r, P.emb, P.probs_out, P.sel, shf); return; }
  if (bx < 800){ lin_body(P.sL1, bx - 544, tid, red); return; }
  if (tid < 64) P.lnstats[tid] = 0.f;
}

// ---------------- final proof fixup: proof[16] = pa + pb ----------------
__global__ __launch_bounds__(256) void fixup_k(const float* __restrict__ pa, const float* __restrict__ pb,
                                               float* __restrict__ out){
  int i = blockIdx.x * 1024 + threadIdx.x * 4;
  float4 va = *(const float4*)(pa + i);
  float4 vb = *(const float4*)(pb + i);
  acc4(va, vb);
  *(float4*)(out + i) = va;
}

// ---------------- batched value head (16 steps) + verifier, grid (64, 17) ----------------
__global__ __launch_bounds__(256) void valver_k(const u16* __restrict__ vw1, const float* __restrict__ vb1,
    const u16* __restrict__ verw1, const float* __restrict__ verb1,
    const float* __restrict__ proof, const float* __restrict__ pfa, const float* __restrict__ pfb,
    float* __restrict__ v1){
  __shared__ float red[4][32][16];
  int t = blockIdx.y;
  LinSeg S = {};
  if (t < 16){
    S.X0 = proof + (size_t)t * 32768; S.K1 = 1024; S.ldx = 1024; S.W1 = vw1; S.ld1 = 2048; S.b1 = vb1;
    S.Y = proof + (size_t)(t + 1) * 32768; S.K2 = 1024; S.W2 = vw1 + 1024; S.ld2 = 2048;
  } else {
    S.X0 = pfa; S.Xa = pfb; S.K1 = 1024; S.ldx = 1024; S.W1 = verw1; S.ld1 = 1024; S.b1 = verb1;
  }
  S.out = v1 + (size_t)t * 32768; S.N = 1024; S.act = 1;
  lin_body(S, blockIdx.x, threadIdx.x, red);
}

__global__ __launch_bounds__(256) void dotsig_b_k(const float* __restrict__ v1,
    const float* __restrict__ w2v, const float* __restrict__ b2v,
    const float* __restrict__ w2ver, const float* __restrict__ b2ver,
    float* __restrict__ out_vals, float* __restrict__ out_valid){
  int t = blockIdx.x;
  const float* w = (t < 16) ? w2v : w2ver;
  const float* bs = (t < 16) ? b2v : b2ver;
  const float* x = v1 + (size_t)t * 32768;
  int b = threadIdx.x >> 3, l8 = threadIdx.x & 7;
  const float* xr = x + (size_t)b * 1024;
  float acc = 0.f;
  #pragma unroll 8
  for (int kk = 0; kk < 32; kk++){
    int k = kk * 32 + l8 * 4;
    float4 xv = *(const float4*)(xr + k);
    float4 wv = *(const float4*)(w + k);
    acc += xv.x * wv.x + xv.y * wv.y + xv.z * wv.z + xv.w * wv.w;
  }
  acc += __shfl_xor(acc, 1); acc += __shfl_xor(acc, 2); acc += __shfl_xor(acc, 4);
  if (l8 == 0){
    float r = sigm_f(acc + bs[0]);
    if (t < 16) out_vals[t * 32 + b] = r; else out_valid[b] = r;
  }
}

// ---------------- batched attn head-mean over all 16 steps ----------------
__global__ __launch_bounds__(256) void attnavg_all_k(const float* __restrict__ afull, float* __restrict__ out){
  int idx = blockIdx.x * 256 + threadIdx.x;     // 16*32768
  int t = idx >> 15, r = idx & 32767;
  int b = r >> 10, s = r & 1023;
  const float* base = afull + (size_t)t * 524288 + (size_t)b * 16384;
  float acc = 0.f;
  #pragma unroll
  for (int h = 0; h < 16; h++) acc += base[h * 1024 + s];
  out[idx] = acc * (1.f / 16.f);
}

extern "C" void kernel_launch(void* const* d_in, const int* in_sizes, int n_in,
                              void* d_out, int out_size, void* d_ws, size_t ws_size,
                              hipStream_t stream) {
  const float* comp      = (const float*)d_in[0];
  const float* rule_w1   = (const float*)d_in[2];
  const float* rule_b1   = (const float*)d_in[3];
  const float* rule_w2   = (const float*)d_in[4];
  const float* rule_b2   = (const float*)d_in[5];
  const float* rule_emb  = (const float*)d_in[6];
  const float* attn_in_w = (const float*)d_in[7];
  const float* attn_in_b = (const float*)d_in[8];
  const float* attn_out_w= (const float*)d_in[9];
  const float* attn_out_b= (const float*)d_in[10];
  const float* wih0 = (const float*)d_in[11];
  const float* whh0 = (const float*)d_in[12];
  const float* bih0 = (const float*)d_in[13];
  const float* bhh0 = (const float*)d_in[14];
  const float* wih1 = (const float*)d_in[15];
  const float* whh1 = (const float*)d_in[16];
  const float* bih1 = (const float*)d_in[17];
  const float* bhh1 = (const float*)d_in[18];
  const float* gen_w1 = (const float*)d_in[19];
  const float* gen_b1 = (const float*)d_in[20];
  const float* ln_g   = (const float*)d_in[21];
  const float* ln_b   = (const float*)d_in[22];
  const float* gen_w2 = (const float*)d_in[23];
  const float* gen_b2 = (const float*)d_in[24];
  const float* val_w1 = (const float*)d_in[25];
  const float* val_b1 = (const float*)d_in[26];
  const float* val_w2 = (const float*)d_in[27];
  const float* val_b2 = (const float*)d_in[28];
  const float* ver_w1 = (const float*)d_in[29];
  const float* ver_b1 = (const float*)d_in[30];
  const float* ver_w2 = (const float*)d_in[31];
  const float* ver_b2 = (const float*)d_in[32];

  float* out_f     = (float*)d_out;
  float* out_proof = out_f;                       // (17,32,1024)
  float* out_valid = out_f + 17 * 32768;          // (32,1)
  float* out_probs = out_valid + 32;              // (16,32,32)
  float* out_vals  = out_probs + 16 * 1024;       // (16,32,1)
  float* out_attn  = out_vals + 16 * 32;          // (16,32,1024)

  char* wp = (char*)d_ws;
  auto carve = [&](size_t bytes) -> void* {
    void* p = (void*)wp; wp += (bytes + 255) & ~(size_t)255; return p;
  };
  u16* Kt    = (u16*)carve((size_t)33554432 * 2);   // bf16 [b][hd][s]
  u16* Vb    = (u16*)carve((size_t)33554432 * 2);   // bf16 [b][h][s][d]
  u16* compb = (u16*)carve((size_t)33554432 * 2);   // bf16 comp; afull_all aliases after gemms
  float* afull_all = (float*)compb;                 // 16 * 512 * 1024 fp32 = 32MB
  u16* rw1b  = (u16*)carve(2097152);
  u16* wqb   = (u16*)carve(2097152);
  u16* wkb   = (u16*)carve(2097152);
  u16* wvb   = (u16*)carve(2097152);
  u16* aowTb = (u16*)carve(2097152);
  u16* wih0b = (u16*)carve(8388608);
  u16* whh0b = (u16*)carve(8388608);
  u16* wih1b = (u16*)carve(8388608);
  u16* whh1b = (u16*)carve(8388608);
  u16* gw1b  = (u16*)carve(4194304);
  u16* gw2b  = (u16*)carve(4194304);
  u16* vw1b  = (u16*)carve(4194304);
  u16* verw1b= (u16*)carve(2097152);
  u16* gaw   = (u16*)carve(4194304);                // gw1 @ aow
  float* bias2 = (float*)carve(8192);
  float* psa[2] = { (float*)carve(131072), (float*)carve(131072) };   // ps partial A
  float* psq[2] = { (float*)carve(131072), (float*)carve(131072) };   // ps partial B
  float* h0b[2] = { (float*)carve(131072), (float*)carve(131072) };
  float* c0b[2] = { (float*)carve(131072), (float*)carve(131072) };
  float* h1b[2] = { (float*)carve(131072), (float*)carve(131072) };
  float* c1b[2] = { (float*)carve(131072), (float*)carve(131072) };
  float* h1act = (float*)carve(131072);
  float* sel   = (float*)carve(131072);
  float* qbuf  = (float*)carve(131072);
  float* ctx0  = (float*)carve(131072);
  float* zbuf  = (float*)carve(262144);
  float* v1buf = (float*)carve(2228224);
  float* lnstats = (float*)carve(256);
  (void)ws_size; (void)in_sizes; (void)n_in; (void)out_size;

  // ---- casts (weights + comp in one launch) + transpose-cast ----
  CastJobs J;
  const float* srcs[13] = { rule_w1, attn_in_w, attn_in_w + 1048576, attn_in_w + 2097152,
                            wih0, whh0, wih1, whh1, gen_w1, gen_w2, val_w1, ver_w1, comp };
  u16* dsts[13] = { rw1b, wqb, wkb, wvb, wih0b, whh0b, wih1b, whh1b, gw1b, gw2b, vw1b, verw1b, compb };
  int sizes[13] = { 1048576, 1048576, 1048576, 1048576,
                    4194304, 4194304, 4194304, 4194304, 2097152, 2097152, 2097152, 1048576, 33554432 };
  int st = 0;
  for (int i = 0; i < 13; i++){ J.s[i] = srcs[i]; J.d[i] = dsts[i]; J.start[i] = st; st += sizes[i] / 1024; }
  J.start[13] = st;
  cast_all_k<<<dim3(st), dim3(256), 0, stream>>>(J);
  tcast_k<<<dim3(1024), dim3(256), 0, stream>>>(attn_out_w, aowTb);

  gemmkv_k<<<dim3(2048, 1, 2), dim3(256), 0, stream>>>(compb, wkb, wvb,
      attn_in_b + 1024, attn_in_b + 2048, Kt, Vb);
  gemmbb_k<<<dim3(16, 8), dim3(256), 0, stream>>>(gw1b, aowTb, gaw);
  bias2_k<<<dim3(64), dim3(256), 0, stream>>>(gen_w1, attn_out_b, gen_b1, bias2);

  init_k<<<dim3(128), dim3(256), 0, stream>>>(comp, psa[0], psq[0], out_proof,
      h0b[0], c0b[0], h1b[0], c1b[0]);

  for (int t = 0; t < 16; t++){
    int cur = t & 1, nx = cur ^ 1;
    float* pa = psa[cur];
    float* pb = psq[cur];
    float* afull_t = afull_all + (size_t)t * 524288;
    // D1: rule h1 (64) + q (64) + LSTM0 (256 gate tiles) + proof[t] fixup (32)
    LinSeg sRule = {}; sRule.X0 = pa; sRule.Xa = pb; sRule.K1 = 1024; sRule.ldx = 1024;
    sRule.W1 = rw1b; sRule.ld1 = 1024; sRule.b1 = rule_b1; sRule.out = h1act; sRule.N = 1024; sRule.act = 1;
    LinSeg sQ = {}; sQ.X0 = pa; sQ.Xa = pb; sQ.K1 = 1024; sQ.ldx = 1024;
    sQ.W1 = wqb; sQ.ld1 = 1024; sQ.b1 = attn_in_b; sQ.out = qbuf; sQ.N = 1024; sQ.act = 2; sQ.scale = 0.125f;
    LinSeg sL0 = {}; sL0.X0 = pa; sL0.Xa = pb; sL0.K1 = 1024; sL0.ldx = 1024;
    sL0.W1 = wih0b; sL0.ld1 = 1024; sL0.b1 = bih0;
    sL0.Y = h0b[cur]; sL0.K2 = 1024; sL0.W2 = whh0b; sL0.ld2 = 1024; sL0.b2 = bhh0;
    sL0.gate = 1; sL0.cprev = c0b[cur]; sL0.cout = c0b[nx]; sL0.hout = h0b[nx];
    step_d1_k<<<dim3(416), dim3(256), 0, stream>>>(sRule, sQ, sL0, pa, pb,
        out_proof + (size_t)t * 32768);
    // D2: attention + rule2 + LSTM1 + LN-stat zero
    D2Params P;
    P.qbuf = qbuf; P.Kt = Kt; P.Vb = Vb; P.afull = afull_t; P.ctx0 = ctx0;
    P.h1a = h1act; P.w2 = rule_w2; P.b2r = rule_b2; P.emb = rule_emb;
    P.probs_out = out_probs + t * 1024; P.sel = sel;
    LinSeg sL1 = {}; sL1.X0 = h0b[nx]; sL1.K1 = 1024; sL1.ldx = 1024;
    sL1.W1 = wih1b; sL1.ld1 = 1024; sL1.b1 = bih1;
    sL1.Y = h1b[cur]; sL1.K2 = 1024; sL1.W2 = whh1b; sL1.ld2 = 1024; sL1.b2 = bhh1;
    sL1.gate = 1; sL1.cprev = c1b[cur]; sL1.cout = c1b[nx]; sL1.hout = h1b[nx];
    P.sL1 = sL1; P.lnstats = lnstats;
    step_d2_k<<<dim3(801), dim3(256), 0, stream>>>(P);
    // D3: z = (ps_a+ps_b+sel+mem)@gw1^T + ctx0@gaw^T + bias2, LN stats (128 tiles)
    LinSeg sG1 = {}; sG1.X0 = pa; sG1.Xa = pb; sG1.Xb = sel; sG1.Xc = h1b[nx];
    sG1.K1 = 1024; sG1.ldx = 1024; sG1.W1 = gw1b; sG1.ld1 = 1024; sG1.b1 = bias2;
    sG1.Y = ctx0; sG1.K2 = 1024; sG1.W2 = gaw; sG1.ld2 = 1024;
    sG1.out = zbuf; sG1.N = 2048; sG1.stats = lnstats;
    linmulti_k<<<dim3(128), dim3(256), 0, stream>>>(sG1, sG1, sG1, 128, 0);
    // D4: psn = gelu(LN(z)) @ gw2^T + b, K-split x2 into partials (128 blocks)
    LinSeg sA = {}; sA.X0 = zbuf; sA.K1 = 1024; sA.ldx = 2048;
    sA.W1 = gw2b; sA.ld1 = 2048; sA.b1 = gen_b2;
    sA.lng = ln_g; sA.lnb = ln_b; sA.lnstats = lnstats;
    sA.out = psa[nx]; sA.N = 1024;
    LinSeg sB = {}; sB.X0 = zbuf + 1024; sB.K1 = 1024; sB.ldx = 2048;
    sB.W1 = gw2b + 1024; sB.ld1 = 2048;
    sB.lng = ln_g + 1024; sB.lnb = ln_b + 1024; sB.lnstats = lnstats;
    sB.out = psq[nx]; sB.N = 1024;
    linmulti_k<<<dim3(128), dim3(256), 0, stream>>>(sA, sB, sB, 64, 64);
  }
  // post-loop: proof[16] fixup, batched value heads + verifier, attn head-mean
  fixup_k<<<dim3(32), dim3(256), 0, stream>>>(psa[0], psq[0], out_proof + (size_t)16 * 32768);
  valver_k<<<dim3(64, 17), dim3(256), 0, stream>>>(vw1b, val_b1, verw1b, ver_b1,
      out_proof, psa[0], psq[0], v1buf);
  dotsig_b_k<<<dim3(17), dim3(256), 0, stream>>>(v1buf, val_w2, val_b2, ver_w2, ver_b2,
      out_vals, out_valid);
  attnavg_all_k<<<dim3(2048), dim3(256), 0, stream>>>(afull_all, out_attn);
}